// Round 1
// baseline (590.694 us; speedup 1.0000x reference)
//
#include <hip/hip_runtime.h>
#include <hip/hip_bf16.h>
#include <cstdint>
#include <cstddef>

// Shapes (fixed by the problem): B=8, S=512, E=H=2048.
#define RTOT 4096      // B*S rows
#define DIM  2048
#define NCAT 6144      // W_f | W_c | W_g columns concatenated
#define LDT  40        // LDS row stride in bf16 elems (32 + 8 pad; 80B, 16B-aligned)

typedef __attribute__((ext_vector_type(8))) short short8;
typedef __attribute__((ext_vector_type(4))) float f32x4;
typedef __attribute__((ext_vector_type(4))) int  int4v;

__device__ __forceinline__ unsigned short f2bf(float f) {
    union { float f; unsigned u; } v; v.f = f;
    unsigned r = v.u + 0x7FFFu + ((v.u >> 16) & 1u);   // RNE
    return (unsigned short)(r >> 16);
}
__device__ __forceinline__ float bf2f(unsigned short h) {
    union { unsigned u; float f; } v; v.u = ((unsigned)h) << 16;
    return v.f;
}
__device__ __forceinline__ float sigmoidf(float z) {
    return 1.0f / (1.0f + expf(-z));
}

// ---------------------------------------------------------------------------
// Build WcatT[j][k] = Wsel[k][j mod 2048] as bf16 (ternary values are exact).
// 64x64 tiles via LDS. grid (6144/64, 2048/64), block 256.
__global__ __launch_bounds__(256) void prep_weights(
    const float* __restrict__ Wf, const float* __restrict__ Wc,
    const float* __restrict__ Wg, unsigned short* __restrict__ WcatT)
{
    __shared__ unsigned short tile[64][65];
    int j0 = blockIdx.x * 64;
    int k0 = blockIdx.y * 64;
    const float* W = (j0 < 2048) ? Wf : (j0 < 4096) ? Wc : Wg;
    int jb = j0 & 2047;
    int c  = threadIdx.x & 63;
    int rr = threadIdx.x >> 6;
#pragma unroll
    for (int p = 0; p < 16; ++p) {
        int kl = p * 4 + rr;
        tile[kl][c] = f2bf(W[(size_t)(k0 + kl) * DIM + jb + c]);
    }
    __syncthreads();
#pragma unroll
    for (int p = 0; p < 16; ++p) {
        int jl = p * 4 + rr;
        WcatT[(size_t)(j0 + jl) * DIM + k0 + c] = tile[c][jl];
    }
}

// Cast W_g (row-major H x E) to bf16 as-is (B^T layout for the cg GEMM).
__global__ __launch_bounds__(256) void cast_wg(
    const float* __restrict__ Wg, unsigned short* __restrict__ out)
{
    int idx = blockIdx.x * 256 + threadIdx.x;
    out[idx] = f2bf(Wg[idx]);
}

// ---------------------------------------------------------------------------
// Per-row: rms_norm + act_quant. Writes Xq (bf16 integer codes), hi/lo split
// of raw x, and the per-row quant scale s. One block per row.
__global__ __launch_bounds__(256) void act_quant_kernel(
    const float* __restrict__ x, const float* __restrict__ scale,
    unsigned short* __restrict__ Xq, unsigned short* __restrict__ Xhi,
    unsigned short* __restrict__ Xlo, float* __restrict__ s_arr)
{
    __shared__ float red1[4];
    __shared__ float tot[2];
    int row = blockIdx.x;
    int tid = threadIdx.x;
    const float* xr = x + (size_t)row * DIM;
    float xs[8], sc[8];
    float sum = 0.f;
#pragma unroll
    for (int i = 0; i < 8; ++i) {
        int e = tid + 256 * i;
        xs[i] = xr[e];
        sc[i] = scale[e];
        sum += xs[i] * xs[i];
    }
#pragma unroll
    for (int off = 32; off > 0; off >>= 1) sum += __shfl_down(sum, off);
    int lane = tid & 63, wv = tid >> 6;
    if (lane == 0) red1[wv] = sum;
    __syncthreads();
    if (tid == 0) tot[0] = red1[0] + red1[1] + red1[2] + red1[3];
    __syncthreads();
    float rms = 1.0f / sqrtf(tot[0] * (1.0f / 2048.0f) + 1e-5f);
    float y[8]; float mx = 0.f;
#pragma unroll
    for (int i = 0; i < 8; ++i) {
        y[i] = xs[i] * rms * sc[i];
        mx = fmaxf(mx, fabsf(y[i]));
    }
#pragma unroll
    for (int off = 32; off > 0; off >>= 1) mx = fmaxf(mx, __shfl_down(mx, off));
    __syncthreads();
    if (lane == 0) red1[wv] = mx;
    __syncthreads();
    if (tid == 0) tot[1] = fmaxf(fmaxf(red1[0], red1[1]), fmaxf(red1[2], red1[3]));
    __syncthreads();
    float s = 127.0f / (tot[1] + 1e-5f);
    s = fminf(fmaxf(s, 0.001f), 1000.0f);
    if (tid == 0) s_arr[row] = s;
#pragma unroll
    for (int i = 0; i < 8; ++i) {
        int e = tid + 256 * i;
        float q = rintf(s * y[i]);                 // RNE, matches jnp.round
        q = fminf(fmaxf(q, -128.0f), 127.0f);
        Xq[(size_t)row * DIM + e] = f2bf(q);       // exact: |q| <= 128 integer
        unsigned short hb = f2bf(xs[i]);
        Xhi[(size_t)row * DIM + e] = hb;
        Xlo[(size_t)row * DIM + e] = f2bf(xs[i] - bf2f(hb));
    }
}

// ---------------------------------------------------------------------------
// GEMM_A: FCG = act( Xq @ WcatT^T / s + bias ).  A: (4096 x 2048) bf16,
// Bt: (6144 x 2048) bf16 (row j holds column j of the K-major weight).
// 128x128x32 tile, 4 waves of 64x64, 16x16x32 bf16 MFMA.
__global__ __launch_bounds__(256) void gemm_fcg(
    const unsigned short* __restrict__ A,
    const unsigned short* __restrict__ Bt,
    const float* __restrict__ s_arr,
    const float* __restrict__ b_f, const float* __restrict__ b_c,
    const float* __restrict__ b_g,
    float* __restrict__ out)   // (4096 x 6144)
{
    __shared__ __align__(16) unsigned short As[128 * LDT];
    __shared__ __align__(16) unsigned short Bs[128 * LDT];
    int m0 = blockIdx.y * 128;
    int n0 = blockIdx.x * 128;
    int tid = threadIdx.x;
    int lane = tid & 63, wv = tid >> 6;
    int wm = (wv >> 1) * 64, wn = (wv & 1) * 64;
    int lr = lane & 15, lq = lane >> 4;

    f32x4 acc[4][4] = {};
    for (int kt = 0; kt < DIM; kt += 32) {
#pragma unroll
        for (int it = 0; it < 2; ++it) {
            int idx = tid + it * 256;
            int row = idx >> 2, ch = idx & 3;
            *(int4v*)(As + row * LDT + ch * 8) =
                *(const int4v*)(A + (size_t)(m0 + row) * DIM + kt + ch * 8);
            *(int4v*)(Bs + row * LDT + ch * 8) =
                *(const int4v*)(Bt + (size_t)(n0 + row) * DIM + kt + ch * 8);
        }
        __syncthreads();
        short8 af[4], bb[4];
#pragma unroll
        for (int i = 0; i < 4; ++i)
            af[i] = *(const short8*)(As + (wm + i * 16 + lr) * LDT + lq * 8);
#pragma unroll
        for (int j = 0; j < 4; ++j)
            bb[j] = *(const short8*)(Bs + (wn + j * 16 + lr) * LDT + lq * 8);
#pragma unroll
        for (int i = 0; i < 4; ++i)
#pragma unroll
            for (int j = 0; j < 4; ++j)
                acc[i][j] = __builtin_amdgcn_mfma_f32_16x16x32_bf16(
                    af[i], bb[j], acc[i][j], 0, 0, 0);
        __syncthreads();
    }
#pragma unroll
    for (int i = 0; i < 4; ++i) {
#pragma unroll
        for (int j = 0; j < 4; ++j) {
            int gcol = n0 + wn + j * 16 + lr;
            int sec = gcol >> 11;
            int jj = gcol & 2047;
            float bias = (sec == 0) ? b_f[jj] : (sec == 1) ? b_c[jj] : b_g[jj];
#pragma unroll
            for (int r = 0; r < 4; ++r) {
                int grow = m0 + wm + i * 16 + lq * 4 + r;
                float z = acc[i][j][r] / s_arr[grow] + bias;
                float sg = sigmoidf(z);
                out[(size_t)grow * NCAT + gcol] = (sec == 1) ? z * sg : sg;
            }
        }
    }
}

// ---------------------------------------------------------------------------
// GEMM_B: CG = sigmoid( (Xhi + Xlo) @ Wg^T ), hi/lo bf16 split of raw x for
// near-fp32 accuracy. Bt = W_g row-major (j, k) = exactly the B^T layout.
__global__ __launch_bounds__(256) void gemm_cg(
    const unsigned short* __restrict__ Ahi,
    const unsigned short* __restrict__ Alo,
    const unsigned short* __restrict__ Bt,
    float* __restrict__ out)   // (4096 x 2048)
{
    __shared__ __align__(16) unsigned short As1[128 * LDT];
    __shared__ __align__(16) unsigned short As2[128 * LDT];
    __shared__ __align__(16) unsigned short Bs[128 * LDT];
    int m0 = blockIdx.y * 128;
    int n0 = blockIdx.x * 128;
    int tid = threadIdx.x;
    int lane = tid & 63, wv = tid >> 6;
    int wm = (wv >> 1) * 64, wn = (wv & 1) * 64;
    int lr = lane & 15, lq = lane >> 4;

    f32x4 acc[4][4] = {};
    for (int kt = 0; kt < DIM; kt += 32) {
#pragma unroll
        for (int it = 0; it < 2; ++it) {
            int idx = tid + it * 256;
            int row = idx >> 2, ch = idx & 3;
            size_t go = (size_t)(m0 + row) * DIM + kt + ch * 8;
            *(int4v*)(As1 + row * LDT + ch * 8) = *(const int4v*)(Ahi + go);
            *(int4v*)(As2 + row * LDT + ch * 8) = *(const int4v*)(Alo + go);
            *(int4v*)(Bs + row * LDT + ch * 8) =
                *(const int4v*)(Bt + (size_t)(n0 + row) * DIM + kt + ch * 8);
        }
        __syncthreads();
        short8 bb[4];
#pragma unroll
        for (int j = 0; j < 4; ++j)
            bb[j] = *(const short8*)(Bs + (wn + j * 16 + lr) * LDT + lq * 8);
#pragma unroll
        for (int i = 0; i < 4; ++i) {
            short8 ah = *(const short8*)(As1 + (wm + i * 16 + lr) * LDT + lq * 8);
            short8 al = *(const short8*)(As2 + (wm + i * 16 + lr) * LDT + lq * 8);
#pragma unroll
            for (int j = 0; j < 4; ++j) {
                acc[i][j] = __builtin_amdgcn_mfma_f32_16x16x32_bf16(
                    al, bb[j], acc[i][j], 0, 0, 0);
                acc[i][j] = __builtin_amdgcn_mfma_f32_16x16x32_bf16(
                    ah, bb[j], acc[i][j], 0, 0, 0);
            }
        }
        __syncthreads();
    }
#pragma unroll
    for (int i = 0; i < 4; ++i)
#pragma unroll
        for (int j = 0; j < 4; ++j)
#pragma unroll
            for (int r = 0; r < 4; ++r) {
                int grow = m0 + wm + i * 16 + lq * 4 + r;
                int gcol = n0 + wn + j * 16 + lr;
                out[(size_t)grow * DIM + gcol] = sigmoidf(acc[i][j][r]);
            }
}

// ---------------------------------------------------------------------------
// Elementwise recurrence over t, 16384 independent (b,h) chains.
// h_new = f*h + (1-f)*c ; o = g*h_new ; h = cg*x + (1-cg)*h_new.
__global__ __launch_bounds__(64) void scan_kernel(
    const float* __restrict__ FCG, const float* __restrict__ CG,
    const float* __restrict__ x, float* __restrict__ out)
{
    int g = blockIdx.x * 64 + threadIdx.x;   // 0..16383
    int b = g >> 11;
    int h = g & 2047;
    const float* fp  = FCG + (size_t)b * 512 * NCAT + h;
    const float* xp  = x   + (size_t)b * 512 * DIM + h;
    const float* cgp = CG  + (size_t)b * 512 * DIM + h;
    float* op        = out + (size_t)b * 512 * DIM + h;
    float hs = 0.f;
    for (int t = 0; t < 512; ++t) {
        float f  = fp[0];
        float c  = fp[2048];
        float gg = fp[4096];
        float cg = cgp[0];
        float xv = xp[0];
        float hnew = f * hs + (1.f - f) * c;
        op[0] = gg * hnew;
        hs = cg * xv + (1.f - cg) * hnew;
        fp += NCAT; xp += DIM; cgp += DIM; op += DIM;
    }
}

// ---------------------------------------------------------------------------
extern "C" void kernel_launch(void* const* d_in, const int* in_sizes, int n_in,
                              void* d_out, int out_size, void* d_ws, size_t ws_size,
                              hipStream_t stream) {
    const float* x     = (const float*)d_in[0];
    const float* rmssc = (const float*)d_in[1];
    const float* W_f   = (const float*)d_in[2];
    const float* W_c   = (const float*)d_in[3];
    const float* W_g   = (const float*)d_in[4];
    const float* b_f   = (const float*)d_in[5];
    const float* b_c   = (const float*)d_in[6];
    const float* b_g   = (const float*)d_in[7];
    float* out = (float*)d_out;

    char* ws = (char*)d_ws;
    size_t off = 0;
    auto alloc = [&](size_t bytes) -> void* {
        void* p = ws + off;
        off += (bytes + 255) & ~(size_t)255;
        return p;
    };
    unsigned short* WcatT = (unsigned short*)alloc((size_t)NCAT * DIM * 2);
    unsigned short* Wgb   = (unsigned short*)alloc((size_t)DIM * DIM * 2);
    unsigned short* Xq    = (unsigned short*)alloc((size_t)RTOT * DIM * 2);
    unsigned short* Xhi   = (unsigned short*)alloc((size_t)RTOT * DIM * 2);
    unsigned short* Xlo   = (unsigned short*)alloc((size_t)RTOT * DIM * 2);
    float* s_arr          = (float*)alloc((size_t)RTOT * 4);
    float* FCG            = (float*)alloc((size_t)RTOT * NCAT * 4);
    float* CG             = (float*)alloc((size_t)RTOT * DIM * 4);

    hipLaunchKernelGGL(prep_weights, dim3(NCAT / 64, DIM / 64), dim3(256), 0, stream,
                       W_f, W_c, W_g, WcatT);
    hipLaunchKernelGGL(cast_wg, dim3((DIM * DIM) / 256), dim3(256), 0, stream,
                       W_g, Wgb);
    hipLaunchKernelGGL(act_quant_kernel, dim3(RTOT), dim3(256), 0, stream,
                       x, rmssc, Xq, Xhi, Xlo, s_arr);
    hipLaunchKernelGGL(gemm_fcg, dim3(NCAT / 128, RTOT / 128), dim3(256), 0, stream,
                       Xq, WcatT, s_arr, b_f, b_c, b_g, FCG);
    hipLaunchKernelGGL(gemm_cg, dim3(DIM / 128, RTOT / 128), dim3(256), 0, stream,
                       Xhi, Xlo, Wgb, CG);
    hipLaunchKernelGGL(scan_kernel, dim3(RTOT * DIM / (512 * 64)), dim3(64), 0, stream,
                       FCG, CG, x, out);
}

// Round 2
// 336.581 us; speedup vs baseline: 1.7550x; 1.7550x over previous
//
#include <hip/hip_runtime.h>
#include <hip/hip_bf16.h>
#include <cstdint>
#include <cstddef>

// Shapes (fixed): B=8, S=512, E=H=2048.
#define RTOT 4096      // B*S rows
#define DIM  2048
#define NCAT 6144      // f | c | g column sections
#define NCHUNK 16      // scan chunks
#define TCHUNK 32      // timesteps per chunk

typedef __attribute__((ext_vector_type(4))) int   int4v;
typedef __attribute__((ext_vector_type(4))) float float4v;

__device__ __forceinline__ float fast_sigmoid(float z) {
    return __builtin_amdgcn_rcpf(1.0f + __expf(-z));
}

// ---------------------------------------------------------------------------
// WcatT[j][k] = (int8)Wsel[k][j mod 2048]; ternary values are exact in i8.
__global__ __launch_bounds__(256) void prep_weights(
    const float* __restrict__ Wf, const float* __restrict__ Wc,
    const float* __restrict__ Wg, signed char* __restrict__ WcatT)
{
    __shared__ signed char tile[64][65];
    int j0 = blockIdx.x * 64;
    int k0 = blockIdx.y * 64;
    const float* W = (j0 < 2048) ? Wf : (j0 < 4096) ? Wc : Wg;
    int jb = j0 & 2047;
    int c  = threadIdx.x & 63;
    int rr = threadIdx.x >> 6;
#pragma unroll
    for (int p = 0; p < 16; ++p) {
        int kl = p * 4 + rr;
        tile[kl][c] = (signed char)(int)W[(size_t)(k0 + kl) * DIM + jb + c];
    }
    __syncthreads();
#pragma unroll
    for (int p = 0; p < 16; ++p) {
        int jl = p * 4 + rr;
        WcatT[(size_t)(j0 + jl) * DIM + k0 + c] = tile[c][jl];
    }
}

// W_g (H x E) cast to i8 as-is (already the B^T layout for the cg GEMM).
__global__ __launch_bounds__(256) void cast_wg(
    const float* __restrict__ Wg, signed char* __restrict__ out)
{
    int idx = (blockIdx.x * 256 + threadIdx.x) * 4;
    float4 v = *(const float4*)(Wg + idx);
    char4 o;
    o.x = (signed char)(int)v.x; o.y = (signed char)(int)v.y;
    o.z = (signed char)(int)v.z; o.w = (signed char)(int)v.w;
    *(char4*)(out + idx) = o;
}

// ---------------------------------------------------------------------------
// Per-row rms_norm + act_quant (int8 codes) + two-plane i8 quant of raw x.
__global__ __launch_bounds__(256) void act_quant_kernel(
    const float* __restrict__ x, const float* __restrict__ scale,
    signed char* __restrict__ Xq, signed char* __restrict__ Q1,
    signed char* __restrict__ Q2, float* __restrict__ s_arr,
    float* __restrict__ s1_arr)
{
    __shared__ float red[12];
    __shared__ float tot[3];
    int row = blockIdx.x;
    int tid = threadIdx.x;
    const float* xr = x + (size_t)row * DIM + tid * 8;
    const float* sr = scale + tid * 8;
    float4 a0 = *(const float4*)(xr);
    float4 a1 = *(const float4*)(xr + 4);
    float4 c0 = *(const float4*)(sr);
    float4 c1 = *(const float4*)(sr + 4);
    float xs[8] = {a0.x, a0.y, a0.z, a0.w, a1.x, a1.y, a1.z, a1.w};
    float sc[8] = {c0.x, c0.y, c0.z, c0.w, c1.x, c1.y, c1.z, c1.w};
    float sum = 0.f, mx2 = 0.f;
#pragma unroll
    for (int i = 0; i < 8; ++i) {
        sum += xs[i] * xs[i];
        mx2 = fmaxf(mx2, fabsf(xs[i]));
    }
#pragma unroll
    for (int off = 32; off > 0; off >>= 1) {
        sum += __shfl_down(sum, off);
        mx2 = fmaxf(mx2, __shfl_down(mx2, off));
    }
    int lane = tid & 63, wv = tid >> 6;
    if (lane == 0) { red[wv] = sum; red[4 + wv] = mx2; }
    __syncthreads();
    if (tid == 0) {
        tot[0] = red[0] + red[1] + red[2] + red[3];
        tot[1] = fmaxf(fmaxf(red[4], red[5]), fmaxf(red[6], red[7]));
    }
    __syncthreads();
    float rms = 1.0f / sqrtf(tot[0] * (1.0f / 2048.0f) + 1e-5f);
    float y[8]; float mx = 0.f;
#pragma unroll
    for (int i = 0; i < 8; ++i) {
        y[i] = (xs[i] * rms) * sc[i];
        mx = fmaxf(mx, fabsf(y[i]));
    }
#pragma unroll
    for (int off = 32; off > 0; off >>= 1) mx = fmaxf(mx, __shfl_down(mx, off));
    if (lane == 0) red[8 + wv] = mx;
    __syncthreads();
    if (tid == 0)
        tot[2] = fmaxf(fmaxf(red[8], red[9]), fmaxf(red[10], red[11]));
    __syncthreads();
    float s = 127.0f / (tot[2] + 1e-5f);
    s = fminf(fmaxf(s, 0.001f), 1000.0f);
    float s1 = 127.0f / (tot[1] + 1e-5f);
    float inv_s1 = 1.0f / s1;
    if (tid == 0) { s_arr[row] = s; s1_arr[row] = s1; }
    signed char q8[8], q1b[8], q2b[8];
#pragma unroll
    for (int i = 0; i < 8; ++i) {
        float q = fminf(fmaxf(rintf(s * y[i]), -128.f), 127.f);
        q8[i] = (signed char)(int)q;
        float qq1 = fminf(fmaxf(rintf(s1 * xs[i]), -128.f), 127.f);
        q1b[i] = (signed char)(int)qq1;
        float r = xs[i] - qq1 * inv_s1;
        float qq2 = fminf(fmaxf(rintf(s1 * 256.f * r), -128.f), 127.f);
        q2b[i] = (signed char)(int)qq2;
    }
    size_t o = (size_t)row * DIM + tid * 8;
    *(int2*)(Xq + o) = *(int2*)q8;
    *(int2*)(Q1 + o) = *(int2*)q1b;
    *(int2*)(Q2 + o) = *(int2*)q2b;
}

// ---------------------------------------------------------------------------
// Stage 128 rows x 64 bytes (i8) into an 8KB LDS tile via global_load_lds,
// with XOR chunk swizzle (chunk ^ ((row>>1)&3)) to kill ds_read conflicts.
__device__ __forceinline__ void stage_tile_i8(
    const signed char* gbase, signed char* lds, int lane, int wv)
{
#pragma unroll
    for (int it = 0; it < 2; ++it) {
        int region = wv + it * 4;
        int r = region * 16 + (lane >> 2);
        int gch = (lane & 3) ^ ((lane >> 3) & 3);
        __builtin_amdgcn_global_load_lds(
            (__attribute__((address_space(1))) void*)(gbase + (size_t)r * DIM + gch * 16),
            (__attribute__((address_space(3))) void*)(lds + region * 1024),
            16, 0, 0);
    }
}

__device__ __forceinline__ int4v frag_ld(const signed char* lds, int R, int lq) {
    return *(const int4v*)(lds + R * 64 + ((lq ^ ((R >> 1) & 3)) * 16));
}

// ---------------------------------------------------------------------------
// GEMM_A: FCG = act( (Xq @ WcatT^T)/s + bias ). i8 MFMA, exact integers.
__global__ __launch_bounds__(256) void gemm_fcg(
    const signed char* __restrict__ A, const signed char* __restrict__ Bt,
    const float* __restrict__ s_arr,
    const float* __restrict__ b_f, const float* __restrict__ b_c,
    const float* __restrict__ b_g, float* __restrict__ out)
{
    __shared__ __align__(16) signed char As[128 * 64];
    __shared__ __align__(16) signed char Bs[128 * 64];
    int m0 = blockIdx.y * 128;
    int n0 = blockIdx.x * 128;
    int tid = threadIdx.x;
    int lane = tid & 63, wv = tid >> 6;
    int wm = (wv >> 1) * 64, wn = (wv & 1) * 64;
    int lr = lane & 15, lq = lane >> 4;

    int4v acc[4][4] = {};
    for (int kt = 0; kt < DIM; kt += 64) {
        stage_tile_i8(A + (size_t)m0 * DIM + kt, As, lane, wv);
        stage_tile_i8(Bt + (size_t)n0 * DIM + kt, Bs, lane, wv);
        __syncthreads();
        int4v af[4], bb[4];
#pragma unroll
        for (int i = 0; i < 4; ++i) af[i] = frag_ld(As, wm + i * 16 + lr, lq);
#pragma unroll
        for (int j = 0; j < 4; ++j) bb[j] = frag_ld(Bs, wn + j * 16 + lr, lq);
#pragma unroll
        for (int i = 0; i < 4; ++i)
#pragma unroll
            for (int j = 0; j < 4; ++j)
                acc[i][j] = __builtin_amdgcn_mfma_i32_16x16x64_i8(
                    af[i], bb[j], acc[i][j], 0, 0, 0);
        __syncthreads();
    }
#pragma unroll
    for (int i = 0; i < 4; ++i) {
        float rinv[4];
#pragma unroll
        for (int r = 0; r < 4; ++r)
            rinv[r] = __builtin_amdgcn_rcpf(s_arr[m0 + wm + i * 16 + lq * 4 + r]);
#pragma unroll
        for (int j = 0; j < 4; ++j) {
            int gcol = n0 + wn + j * 16 + lr;
            int sec = gcol >> 11;
            int jj = gcol & 2047;
            float bias = (sec == 0) ? b_f[jj] : (sec == 1) ? b_c[jj] : b_g[jj];
#pragma unroll
            for (int r = 0; r < 4; ++r) {
                int grow = m0 + wm + i * 16 + lq * 4 + r;
                float z = fmaf((float)acc[i][j][r], rinv[r], bias);
                float sg = fast_sigmoid(z);
                out[(size_t)grow * NCAT + gcol] = (sec == 1) ? z * sg : sg;
            }
        }
    }
}

// ---------------------------------------------------------------------------
// GEMM_B: CG = sigmoid( ((Q1 + Q2/256) @ Wg^T)/s1 ). Two-plane i8 residual
// quantization of raw x — near-fp32 exact.
__global__ __launch_bounds__(256) void gemm_cg(
    const signed char* __restrict__ Q1, const signed char* __restrict__ Q2,
    const signed char* __restrict__ Bt, const float* __restrict__ s1_arr,
    float* __restrict__ out)
{
    __shared__ __align__(16) signed char As1[128 * 64];
    __shared__ __align__(16) signed char As2[128 * 64];
    __shared__ __align__(16) signed char Bs[128 * 64];
    int m0 = blockIdx.y * 128;
    int n0 = blockIdx.x * 128;
    int tid = threadIdx.x;
    int lane = tid & 63, wv = tid >> 6;
    int wm = (wv >> 1) * 64, wn = (wv & 1) * 64;
    int lr = lane & 15, lq = lane >> 4;

    int4v acc1[4][4] = {};
    int4v acc2[4][4] = {};
    for (int kt = 0; kt < DIM; kt += 64) {
        stage_tile_i8(Q1 + (size_t)m0 * DIM + kt, As1, lane, wv);
        stage_tile_i8(Q2 + (size_t)m0 * DIM + kt, As2, lane, wv);
        stage_tile_i8(Bt + (size_t)n0 * DIM + kt, Bs, lane, wv);
        __syncthreads();
        int4v a1[4], a2[4], bb[4];
#pragma unroll
        for (int i = 0; i < 4; ++i) {
            a1[i] = frag_ld(As1, wm + i * 16 + lr, lq);
            a2[i] = frag_ld(As2, wm + i * 16 + lr, lq);
        }
#pragma unroll
        for (int j = 0; j < 4; ++j) bb[j] = frag_ld(Bs, wn + j * 16 + lr, lq);
#pragma unroll
        for (int i = 0; i < 4; ++i)
#pragma unroll
            for (int j = 0; j < 4; ++j) {
                acc1[i][j] = __builtin_amdgcn_mfma_i32_16x16x64_i8(
                    a1[i], bb[j], acc1[i][j], 0, 0, 0);
                acc2[i][j] = __builtin_amdgcn_mfma_i32_16x16x64_i8(
                    a2[i], bb[j], acc2[i][j], 0, 0, 0);
            }
        __syncthreads();
    }
#pragma unroll
    for (int i = 0; i < 4; ++i) {
        float rinv[4];
#pragma unroll
        for (int r = 0; r < 4; ++r)
            rinv[r] = __builtin_amdgcn_rcpf(s1_arr[m0 + wm + i * 16 + lq * 4 + r]);
#pragma unroll
        for (int j = 0; j < 4; ++j) {
            int gcol = n0 + wn + j * 16 + lr;
#pragma unroll
            for (int r = 0; r < 4; ++r) {
                int grow = m0 + wm + i * 16 + lq * 4 + r;
                float zs = (float)acc1[i][j][r] + (float)acc2[i][j][r] * (1.f / 256.f);
                out[(size_t)grow * DIM + gcol] = fast_sigmoid(zs * rinv[r]);
            }
        }
    }
}

// ---------------------------------------------------------------------------
// Scan phase 1: per (chunk, chain) compose A_t,B_t over 32 steps.
// h_t = A_t h_{t-1} + B_t,  A=(1-cg)f,  B=(1-cg)(1-f)c + cg*x.
__global__ __launch_bounds__(256) void scan_partial(
    const float* __restrict__ FCG, const float* __restrict__ CG,
    const float* __restrict__ x, float2* __restrict__ PQ)
{
    int h = blockIdx.x * 256 + threadIdx.x;
    int c = blockIdx.y;
    int b = blockIdx.z;
    size_t r0 = (size_t)(b * 512 + c * TCHUNK);
    const float* fp  = FCG + r0 * NCAT + h;
    const float* cgp = CG  + r0 * DIM + h;
    const float* xp  = x   + r0 * DIM + h;
    float P = 1.f, Q = 0.f;
#pragma unroll 4
    for (int t = 0; t < TCHUNK; ++t) {
        float f  = fp[0];
        float cc = fp[2048];
        float cg = cgp[0];
        float xv = xp[0];
        float A  = (1.f - cg) * f;
        float Bv = (1.f - cg) * ((1.f - f) * cc) + cg * xv;
        P = A * P;
        Q = fmaf(A, Q, Bv);
        fp += NCAT; cgp += DIM; xp += DIM;
    }
    PQ[(size_t)c * 16384 + b * 2048 + h] = make_float2(P, Q);
}

// Scan phase 2: combine chunk summaries -> chunk-entry h.
__global__ __launch_bounds__(256) void scan_mid(
    const float2* __restrict__ PQ, float* __restrict__ Hin)
{
    int g = blockIdx.x * 256 + threadIdx.x;   // chain 0..16383
    float h = 0.f;
#pragma unroll
    for (int c = 0; c < NCHUNK; ++c) {
        float2 pq = PQ[(size_t)c * 16384 + g];
        Hin[(size_t)c * 16384 + g] = h;
        h = fmaf(pq.x, h, pq.y);
    }
}

// Scan phase 3: replay chunk with known entry h, emit o_t.
__global__ __launch_bounds__(256) void scan_final(
    const float* __restrict__ FCG, const float* __restrict__ CG,
    const float* __restrict__ x, const float* __restrict__ Hin,
    float* __restrict__ out)
{
    int h = blockIdx.x * 256 + threadIdx.x;
    int c = blockIdx.y;
    int b = blockIdx.z;
    size_t r0 = (size_t)(b * 512 + c * TCHUNK);
    const float* fp  = FCG + r0 * NCAT + h;
    const float* cgp = CG  + r0 * DIM + h;
    const float* xp  = x   + r0 * DIM + h;
    float*       op  = out + r0 * DIM + h;
    float hs = Hin[(size_t)c * 16384 + b * 2048 + h];
#pragma unroll 4
    for (int t = 0; t < TCHUNK; ++t) {
        float f  = fp[0];
        float cc = fp[2048];
        float gg = fp[4096];
        float cg = cgp[0];
        float xv = xp[0];
        float hnew = f * hs + (1.f - f) * cc;
        op[0] = gg * hnew;
        hs = cg * xv + (1.f - cg) * hnew;
        fp += NCAT; cgp += DIM; xp += DIM; op += DIM;
    }
}

// ---------------------------------------------------------------------------
extern "C" void kernel_launch(void* const* d_in, const int* in_sizes, int n_in,
                              void* d_out, int out_size, void* d_ws, size_t ws_size,
                              hipStream_t stream) {
    const float* x     = (const float*)d_in[0];
    const float* rmssc = (const float*)d_in[1];
    const float* W_f   = (const float*)d_in[2];
    const float* W_c   = (const float*)d_in[3];
    const float* W_g   = (const float*)d_in[4];
    const float* b_f   = (const float*)d_in[5];
    const float* b_c   = (const float*)d_in[6];
    const float* b_g   = (const float*)d_in[7];
    float* out = (float*)d_out;

    char* ws = (char*)d_ws;
    size_t off = 0;
    auto alloc = [&](size_t bytes) -> void* {
        void* p = ws + off;
        off += (bytes + 255) & ~(size_t)255;
        return p;
    };
    signed char* WcatT = (signed char*)alloc((size_t)NCAT * DIM);
    signed char* Wgb   = (signed char*)alloc((size_t)DIM * DIM);
    signed char* Xq    = (signed char*)alloc((size_t)RTOT * DIM);
    signed char* Q1    = (signed char*)alloc((size_t)RTOT * DIM);
    signed char* Q2    = (signed char*)alloc((size_t)RTOT * DIM);
    float* s_arr       = (float*)alloc((size_t)RTOT * 4);
    float* s1_arr      = (float*)alloc((size_t)RTOT * 4);
    float* FCG         = (float*)alloc((size_t)RTOT * NCAT * 4);
    float* CG          = (float*)alloc((size_t)RTOT * DIM * 4);
    float2* PQ         = (float2*)alloc((size_t)NCHUNK * 16384 * 8);
    float* Hin         = (float*)alloc((size_t)NCHUNK * 16384 * 4);

    hipLaunchKernelGGL(prep_weights, dim3(NCAT / 64, DIM / 64), dim3(256), 0, stream,
                       W_f, W_c, W_g, WcatT);
    hipLaunchKernelGGL(cast_wg, dim3((DIM * DIM) / 1024), dim3(256), 0, stream,
                       W_g, Wgb);
    hipLaunchKernelGGL(act_quant_kernel, dim3(RTOT), dim3(256), 0, stream,
                       x, rmssc, Xq, Q1, Q2, s_arr, s1_arr);
    hipLaunchKernelGGL(gemm_fcg, dim3(NCAT / 128, RTOT / 128), dim3(256), 0, stream,
                       Xq, WcatT, s_arr, b_f, b_c, b_g, FCG);
    hipLaunchKernelGGL(gemm_cg, dim3(DIM / 128, RTOT / 128), dim3(256), 0, stream,
                       Q1, Q2, Wgb, s1_arr, CG);
    hipLaunchKernelGGL(scan_partial, dim3(DIM / 256, NCHUNK, 8), dim3(256), 0, stream,
                       FCG, CG, x, PQ);
    hipLaunchKernelGGL(scan_mid, dim3(16384 / 256), dim3(256), 0, stream,
                       PQ, Hin);
    hipLaunchKernelGGL(scan_final, dim3(DIM / 256, NCHUNK, 8), dim3(256), 0, stream,
                       FCG, CG, x, Hin, out);
}

// Round 3
// 303.424 us; speedup vs baseline: 1.9468x; 1.1093x over previous
//
#include <hip/hip_runtime.h>
#include <hip/hip_bf16.h>
#include <cstdint>
#include <cstddef>

// Shapes (fixed): B=8, S=512, E=H=2048.
#define RTOT 4096      // B*S rows
#define DIM  2048
#define NCAT 6144      // f | c | g column sections
#define NCHUNK 16      // scan chunks
#define TCHUNK 32      // timesteps per chunk

typedef __attribute__((ext_vector_type(4))) int int4v;

__device__ __forceinline__ float fast_sigmoid(float z) {
    return __builtin_amdgcn_rcpf(1.0f + __expf(-z));
}
__device__ __forceinline__ unsigned short f2h(float f) {
    union { _Float16 h; unsigned short u; } v; v.h = (_Float16)f; return v.u;
}
__device__ __forceinline__ float h2f(unsigned short u) {
    union { _Float16 h; unsigned short u; } v; v.u = u; return (float)v.h;
}

// ---------------------------------------------------------------------------
// WcatT[j][k] = (int8)Wsel[k][j mod 2048]; ternary values exact in i8.
__global__ __launch_bounds__(256) void prep_weights(
    const float* __restrict__ Wf, const float* __restrict__ Wc,
    const float* __restrict__ Wg, signed char* __restrict__ WcatT)
{
    __shared__ signed char tile[64][65];
    int j0 = blockIdx.x * 64;
    int k0 = blockIdx.y * 64;
    const float* W = (j0 < 2048) ? Wf : (j0 < 4096) ? Wc : Wg;
    int jb = j0 & 2047;
    int c  = threadIdx.x & 63;
    int rr = threadIdx.x >> 6;
#pragma unroll
    for (int p = 0; p < 16; ++p) {
        int kl = p * 4 + rr;
        tile[kl][c] = (signed char)(int)W[(size_t)(k0 + kl) * DIM + jb + c];
    }
    __syncthreads();
#pragma unroll
    for (int p = 0; p < 16; ++p) {
        int jl = p * 4 + rr;
        WcatT[(size_t)(j0 + jl) * DIM + k0 + c] = tile[c][jl];
    }
}

// W_g (H x E) cast to i8 as-is (already B^T layout for the cg GEMM).
__global__ __launch_bounds__(256) void cast_wg(
    const float* __restrict__ Wg, signed char* __restrict__ out)
{
    int idx = (blockIdx.x * 256 + threadIdx.x) * 4;
    float4 v = *(const float4*)(Wg + idx);
    char4 o;
    o.x = (signed char)(int)v.x; o.y = (signed char)(int)v.y;
    o.z = (signed char)(int)v.z; o.w = (signed char)(int)v.w;
    *(char4*)(out + idx) = o;
}

// ---------------------------------------------------------------------------
// Per-row rms_norm + act_quant (int8 codes) + two-plane i8 quant of raw x.
__global__ __launch_bounds__(256) void act_quant_kernel(
    const float* __restrict__ x, const float* __restrict__ scale,
    signed char* __restrict__ Xq, signed char* __restrict__ Q1,
    signed char* __restrict__ Q2, float* __restrict__ s_arr,
    float* __restrict__ s1_arr)
{
    __shared__ float red[12];
    __shared__ float tot[3];
    int row = blockIdx.x;
    int tid = threadIdx.x;
    const float* xr = x + (size_t)row * DIM + tid * 8;
    const float* sr = scale + tid * 8;
    float4 a0 = *(const float4*)(xr);
    float4 a1 = *(const float4*)(xr + 4);
    float4 c0 = *(const float4*)(sr);
    float4 c1 = *(const float4*)(sr + 4);
    float xs[8] = {a0.x, a0.y, a0.z, a0.w, a1.x, a1.y, a1.z, a1.w};
    float sc[8] = {c0.x, c0.y, c0.z, c0.w, c1.x, c1.y, c1.z, c1.w};
    float sum = 0.f, mx2 = 0.f;
#pragma unroll
    for (int i = 0; i < 8; ++i) {
        sum += xs[i] * xs[i];
        mx2 = fmaxf(mx2, fabsf(xs[i]));
    }
#pragma unroll
    for (int off = 32; off > 0; off >>= 1) {
        sum += __shfl_down(sum, off);
        mx2 = fmaxf(mx2, __shfl_down(mx2, off));
    }
    int lane = tid & 63, wv = tid >> 6;
    if (lane == 0) { red[wv] = sum; red[4 + wv] = mx2; }
    __syncthreads();
    if (tid == 0) {
        tot[0] = red[0] + red[1] + red[2] + red[3];
        tot[1] = fmaxf(fmaxf(red[4], red[5]), fmaxf(red[6], red[7]));
    }
    __syncthreads();
    float rms = 1.0f / sqrtf(tot[0] * (1.0f / 2048.0f) + 1e-5f);
    float y[8]; float mx = 0.f;
#pragma unroll
    for (int i = 0; i < 8; ++i) {
        y[i] = (xs[i] * rms) * sc[i];
        mx = fmaxf(mx, fabsf(y[i]));
    }
#pragma unroll
    for (int off = 32; off > 0; off >>= 1) mx = fmaxf(mx, __shfl_down(mx, off));
    if (lane == 0) red[8 + wv] = mx;
    __syncthreads();
    if (tid == 0)
        tot[2] = fmaxf(fmaxf(red[8], red[9]), fmaxf(red[10], red[11]));
    __syncthreads();
    float s = 127.0f / (tot[2] + 1e-5f);
    s = fminf(fmaxf(s, 0.001f), 1000.0f);
    float s1 = 127.0f / (tot[1] + 1e-5f);
    float inv_s1 = 1.0f / s1;
    if (tid == 0) { s_arr[row] = s; s1_arr[row] = s1; }
    signed char q8[8], q1b[8], q2b[8];
#pragma unroll
    for (int i = 0; i < 8; ++i) {
        float q = fminf(fmaxf(rintf(s * y[i]), -128.f), 127.f);
        q8[i] = (signed char)(int)q;
        float qq1 = fminf(fmaxf(rintf(s1 * xs[i]), -128.f), 127.f);
        q1b[i] = (signed char)(int)qq1;
        float r = xs[i] - qq1 * inv_s1;
        float qq2 = fminf(fmaxf(rintf(s1 * 256.f * r), -128.f), 127.f);
        q2b[i] = (signed char)(int)qq2;
    }
    size_t o = (size_t)row * DIM + tid * 8;
    *(int2*)(Xq + o) = *(int2*)q8;
    *(int2*)(Q1 + o) = *(int2*)q1b;
    *(int2*)(Q2 + o) = *(int2*)q2b;
}

// ---------------------------------------------------------------------------
// global_load_lds staging of a 16-row x 64-byte region per wave-issue, with
// XOR chunk swizzle LDS[row][ch] = G[row][ch ^ ((row>>1)&3)] (0 conflicts,
// verified round 2).
#define GLDS(gp, lp) __builtin_amdgcn_global_load_lds( \
    (__attribute__((address_space(1))) const void*)(gp), \
    (__attribute__((address_space(3))) void*)(lp), 16, 0, 0)

__device__ __forceinline__ int4v frag_ld(const signed char* lds, int R, int lq) {
    return *(const int4v*)(lds + R * 64 + ((lq ^ ((R >> 1) & 3)) * 16));
}

// ---------------------------------------------------------------------------
// GEMM_A: FCG(fp16) = act( (Xq @ WcatT^T)/s + bias ). i8 MFMA, exact ints.
// 128x128 tile, 4 waves of 64x64.
__global__ __launch_bounds__(256) void gemm_fcg(
    const signed char* __restrict__ A, const signed char* __restrict__ Bt,
    const float* __restrict__ s_arr,
    const float* __restrict__ b_f, const float* __restrict__ b_c,
    const float* __restrict__ b_g, unsigned short* __restrict__ out)
{
    __shared__ __align__(16) signed char As[128 * 64];
    __shared__ __align__(16) signed char Bs[128 * 64];
    int m0 = blockIdx.y * 128;
    int n0 = blockIdx.x * 128;
    int tid = threadIdx.x;
    int lane = tid & 63, wv = tid >> 6;
    int wm = (wv >> 1) * 64, wn = (wv & 1) * 64;
    int lr = lane & 15, lq = lane >> 4;
    int rA = (lane >> 2);
    int gch = ((lane & 3) ^ ((lane >> 3) & 3)) * 16;

    int4v acc[4][4] = {};
    for (int kt = 0; kt < DIM; kt += 64) {
#pragma unroll
        for (int it = 0; it < 2; ++it) {
            int region = wv + it * 4;
            int r = region * 16 + rA;
            GLDS(A  + (size_t)(m0 + r) * DIM + kt + gch, As + region * 1024);
            GLDS(Bt + (size_t)(n0 + r) * DIM + kt + gch, Bs + region * 1024);
        }
        __syncthreads();
        int4v af[4], bb[4];
#pragma unroll
        for (int i = 0; i < 4; ++i) af[i] = frag_ld(As, wm + i * 16 + lr, lq);
#pragma unroll
        for (int j = 0; j < 4; ++j) bb[j] = frag_ld(Bs, wn + j * 16 + lr, lq);
#pragma unroll
        for (int i = 0; i < 4; ++i)
#pragma unroll
            for (int j = 0; j < 4; ++j)
                acc[i][j] = __builtin_amdgcn_mfma_i32_16x16x64_i8(
                    af[i], bb[j], acc[i][j], 0, 0, 0);
        __syncthreads();
    }
#pragma unroll
    for (int i = 0; i < 4; ++i) {
        float rinv[4];
#pragma unroll
        for (int r = 0; r < 4; ++r)
            rinv[r] = __builtin_amdgcn_rcpf(s_arr[m0 + wm + i * 16 + lq * 4 + r]);
#pragma unroll
        for (int j = 0; j < 4; ++j) {
            int gcol = n0 + wn + j * 16 + lr;
            int sec = gcol >> 11;
            int jj = gcol & 2047;
            float bias = (sec == 0) ? b_f[jj] : (sec == 1) ? b_c[jj] : b_g[jj];
#pragma unroll
            for (int r = 0; r < 4; ++r) {
                int grow = m0 + wm + i * 16 + lq * 4 + r;
                float z = fmaf((float)acc[i][j][r], rinv[r], bias);
                float sg = fast_sigmoid(z);
                out[(size_t)grow * NCAT + gcol] = f2h((sec == 1) ? z * sg : sg);
            }
        }
    }
}

// ---------------------------------------------------------------------------
// GEMM_B: cg = sigmoid( ((Q1 + Q2/256) @ Wg^T)/s1 ); emits U=cg*x, V=1-cg
// as fp16. 64x128 tile, 4 waves of 32x64 -> 1024 blocks, 64-VGPR accs.
__global__ __launch_bounds__(256) void gemm_cg(
    const signed char* __restrict__ Q1, const signed char* __restrict__ Q2,
    const signed char* __restrict__ Bt, const float* __restrict__ s1_arr,
    const float* __restrict__ x,
    unsigned short* __restrict__ U, unsigned short* __restrict__ V)
{
    __shared__ __align__(16) signed char As1[64 * 64];
    __shared__ __align__(16) signed char As2[64 * 64];
    __shared__ __align__(16) signed char Bs[128 * 64];
    int m0 = blockIdx.y * 64;
    int n0 = blockIdx.x * 128;
    int tid = threadIdx.x;
    int lane = tid & 63, wv = tid >> 6;
    int wm = (wv >> 1) * 32, wn = (wv & 1) * 64;
    int lr = lane & 15, lq = lane >> 4;
    int rA = wv * 16 + (lane >> 2);          // 0..63
    int gch = ((lane & 3) ^ ((lane >> 3) & 3)) * 16;

    int4v acc1[2][4] = {};
    int4v acc2[2][4] = {};
    for (int kt = 0; kt < DIM; kt += 64) {
        GLDS(Q1 + (size_t)(m0 + rA) * DIM + kt + gch, As1 + wv * 1024);
        GLDS(Q2 + (size_t)(m0 + rA) * DIM + kt + gch, As2 + wv * 1024);
        GLDS(Bt + (size_t)(n0 + rA) * DIM + kt + gch, Bs + wv * 1024);
        GLDS(Bt + (size_t)(n0 + 64 + rA) * DIM + kt + gch, Bs + 4096 + wv * 1024);
        __syncthreads();
        int4v bb[4];
#pragma unroll
        for (int j = 0; j < 4; ++j) bb[j] = frag_ld(Bs, wn + j * 16 + lr, lq);
#pragma unroll
        for (int i = 0; i < 2; ++i) {
            int4v a1 = frag_ld(As1, wm + i * 16 + lr, lq);
            int4v a2 = frag_ld(As2, wm + i * 16 + lr, lq);
#pragma unroll
            for (int j = 0; j < 4; ++j) {
                acc1[i][j] = __builtin_amdgcn_mfma_i32_16x16x64_i8(
                    a1, bb[j], acc1[i][j], 0, 0, 0);
                acc2[i][j] = __builtin_amdgcn_mfma_i32_16x16x64_i8(
                    a2, bb[j], acc2[i][j], 0, 0, 0);
            }
        }
        __syncthreads();
    }
#pragma unroll
    for (int i = 0; i < 2; ++i) {
        float rinv[4];
#pragma unroll
        for (int r = 0; r < 4; ++r)
            rinv[r] = __builtin_amdgcn_rcpf(s1_arr[m0 + wm + i * 16 + lq * 4 + r]);
#pragma unroll
        for (int j = 0; j < 4; ++j) {
            int gcol = n0 + wn + j * 16 + lr;
#pragma unroll
            for (int r = 0; r < 4; ++r) {
                int grow = m0 + wm + i * 16 + lq * 4 + r;
                float zs = (float)acc1[i][j][r] + (float)acc2[i][j][r] * (1.f / 256.f);
                float cg = fast_sigmoid(zs * rinv[r]);
                float xv = x[(size_t)grow * DIM + gcol];
                U[(size_t)grow * DIM + gcol] = f2h(cg * xv);
                V[(size_t)grow * DIM + gcol] = f2h(1.f - cg);
            }
        }
    }
}

// ---------------------------------------------------------------------------
// Scan phase 1: h_t = A_t h_{t-1} + B_t with A = v*f, B = v*(1-f)*c + u.
__global__ __launch_bounds__(256) void scan_partial(
    const unsigned short* __restrict__ FCG, const unsigned short* __restrict__ U,
    const unsigned short* __restrict__ V, float2* __restrict__ PQ)
{
    int h = blockIdx.x * 256 + threadIdx.x;
    int c = blockIdx.y;
    int b = blockIdx.z;
    size_t r0 = (size_t)(b * 512 + c * TCHUNK);
    const unsigned short* fp = FCG + r0 * NCAT + h;
    const unsigned short* up = U + r0 * DIM + h;
    const unsigned short* vp = V + r0 * DIM + h;
    float P = 1.f, Q = 0.f;
#pragma unroll 4
    for (int t = 0; t < TCHUNK; ++t) {
        float f  = h2f(fp[0]);
        float cc = h2f(fp[2048]);
        float u  = h2f(up[0]);
        float v  = h2f(vp[0]);
        float A  = v * f;
        float Bv = fmaf(v * (1.f - f), cc, u);
        P = A * P;
        Q = fmaf(A, Q, Bv);
        fp += NCAT; up += DIM; vp += DIM;
    }
    PQ[(size_t)c * 16384 + b * 2048 + h] = make_float2(P, Q);
}

// Scan phase 2: combine chunk summaries -> chunk-entry h.
__global__ __launch_bounds__(256) void scan_mid(
    const float2* __restrict__ PQ, float* __restrict__ Hin)
{
    int g = blockIdx.x * 256 + threadIdx.x;
    float h = 0.f;
#pragma unroll
    for (int c = 0; c < NCHUNK; ++c) {
        float2 pq = PQ[(size_t)c * 16384 + g];
        Hin[(size_t)c * 16384 + g] = h;
        h = fmaf(pq.x, h, pq.y);
    }
}

// Scan phase 3: replay chunk with known entry h, emit o_t (fp32).
__global__ __launch_bounds__(256) void scan_final(
    const unsigned short* __restrict__ FCG, const unsigned short* __restrict__ U,
    const unsigned short* __restrict__ V, const float* __restrict__ Hin,
    float* __restrict__ out)
{
    int h = blockIdx.x * 256 + threadIdx.x;
    int c = blockIdx.y;
    int b = blockIdx.z;
    size_t r0 = (size_t)(b * 512 + c * TCHUNK);
    const unsigned short* fp = FCG + r0 * NCAT + h;
    const unsigned short* up = U + r0 * DIM + h;
    const unsigned short* vp = V + r0 * DIM + h;
    float* op = out + r0 * DIM + h;
    float hs = Hin[(size_t)c * 16384 + b * 2048 + h];
#pragma unroll 4
    for (int t = 0; t < TCHUNK; ++t) {
        float f  = h2f(fp[0]);
        float cc = h2f(fp[2048]);
        float gg = h2f(fp[4096]);
        float u  = h2f(up[0]);
        float v  = h2f(vp[0]);
        float hnew = f * hs + (1.f - f) * cc;
        op[0] = gg * hnew;
        hs = fmaf(v, hnew, u);
        fp += NCAT; up += DIM; vp += DIM; op += DIM;
    }
}

// ---------------------------------------------------------------------------
extern "C" void kernel_launch(void* const* d_in, const int* in_sizes, int n_in,
                              void* d_out, int out_size, void* d_ws, size_t ws_size,
                              hipStream_t stream) {
    const float* x     = (const float*)d_in[0];
    const float* rmssc = (const float*)d_in[1];
    const float* W_f   = (const float*)d_in[2];
    const float* W_c   = (const float*)d_in[3];
    const float* W_g   = (const float*)d_in[4];
    const float* b_f   = (const float*)d_in[5];
    const float* b_c   = (const float*)d_in[6];
    const float* b_g   = (const float*)d_in[7];
    float* out = (float*)d_out;

    char* ws = (char*)d_ws;
    size_t off = 0;
    auto alloc = [&](size_t bytes) -> void* {
        void* p = ws + off;
        off += (bytes + 255) & ~(size_t)255;
        return p;
    };
    signed char* WcatT = (signed char*)alloc((size_t)NCAT * DIM);
    signed char* Wgb   = (signed char*)alloc((size_t)DIM * DIM);
    signed char* Xq    = (signed char*)alloc((size_t)RTOT * DIM);
    signed char* Q1    = (signed char*)alloc((size_t)RTOT * DIM);
    signed char* Q2    = (signed char*)alloc((size_t)RTOT * DIM);
    float* s_arr       = (float*)alloc((size_t)RTOT * 4);
    float* s1_arr      = (float*)alloc((size_t)RTOT * 4);
    unsigned short* FCG = (unsigned short*)alloc((size_t)RTOT * NCAT * 2);
    unsigned short* U   = (unsigned short*)alloc((size_t)RTOT * DIM * 2);
    unsigned short* V   = (unsigned short*)alloc((size_t)RTOT * DIM * 2);
    float2* PQ         = (float2*)alloc((size_t)NCHUNK * 16384 * 8);
    float* Hin         = (float*)alloc((size_t)NCHUNK * 16384 * 4);

    hipLaunchKernelGGL(prep_weights, dim3(NCAT / 64, DIM / 64), dim3(256), 0, stream,
                       W_f, W_c, W_g, WcatT);
    hipLaunchKernelGGL(cast_wg, dim3((DIM * DIM) / 1024), dim3(256), 0, stream,
                       W_g, Wgb);
    hipLaunchKernelGGL(act_quant_kernel, dim3(RTOT), dim3(256), 0, stream,
                       x, rmssc, Xq, Q1, Q2, s_arr, s1_arr);
    hipLaunchKernelGGL(gemm_fcg, dim3(NCAT / 128, RTOT / 128), dim3(256), 0, stream,
                       Xq, WcatT, s_arr, b_f, b_c, b_g, FCG);
    hipLaunchKernelGGL(gemm_cg, dim3(DIM / 128, RTOT / 64), dim3(256), 0, stream,
                       Q1, Q2, Wgb, s1_arr, x, U, V);
    hipLaunchKernelGGL(scan_partial, dim3(DIM / 256, NCHUNK, 8), dim3(256), 0, stream,
                       FCG, U, V, PQ);
    hipLaunchKernelGGL(scan_mid, dim3(16384 / 256), dim3(256), 0, stream,
                       PQ, Hin);
    hipLaunchKernelGGL(scan_final, dim3(DIM / 256, NCHUNK, 8), dim3(256), 0, stream,
                       FCG, U, V, Hin, out);
}

// Round 4
// 297.285 us; speedup vs baseline: 1.9870x; 1.0207x over previous
//
#include <hip/hip_runtime.h>
#include <hip/hip_bf16.h>
#include <cstdint>
#include <cstddef>

// Shapes (fixed): B=8, S=512, E=H=2048.
#define RTOT 4096      // B*S rows
#define DIM  2048
#define NCAT 6144      // f | c | g column sections
#define NCHUNK 16      // scan chunks
#define TCHUNK 32      // timesteps per chunk

typedef __attribute__((ext_vector_type(4))) int int4v;

__device__ __forceinline__ float fast_sigmoid(float z) {
    return __builtin_amdgcn_rcpf(1.0f + __expf(-z));
}
__device__ __forceinline__ unsigned short f2h(float f) {
    union { _Float16 h; unsigned short u; } v; v.h = (_Float16)f; return v.u;
}
__device__ __forceinline__ float h2f(unsigned short u) {
    union { _Float16 h; unsigned short u; } v; v.u = u; return (float)v.h;
}

// global -> LDS DMA, 16B/lane; dest = wave-uniform base + lane*16.
#define GLDS(gp, lp) __builtin_amdgcn_global_load_lds( \
    (__attribute__((address_space(1))) const void*)(gp), \
    (__attribute__((address_space(3))) void*)(lp), 16, 0, 0)

// LDS[r][slot s] = G[r][s ^ ((r>>1)&3)]  (0 bank conflicts, verified r2/r3)
__device__ __forceinline__ int4v frag_ld(const signed char* lds, int R, int lq) {
    return *(const int4v*)(lds + R * 64 + ((lq ^ ((R >> 1) & 3)) * 16));
}

// ---------------------------------------------------------------------------
// prep_all: one branched kernel.
//   blocks [0,3072)    : WcatT[j][k] = (i8)Wsel[k][j&2047]   (64x64 tiles)
//   blocks [3072,4096) : Wgb = (i8)W_g row-major
//   blocks [4096,8192) : per-row rmsnorm+act_quant -> Xq, and 2-plane i8
//                        quant of raw x -> Q1,Q2, scales s,s1
__global__ __launch_bounds__(256) void prep_all(
    const float* __restrict__ x, const float* __restrict__ scale,
    const float* __restrict__ Wf, const float* __restrict__ Wc,
    const float* __restrict__ Wg,
    signed char* __restrict__ WcatT, signed char* __restrict__ Wgb,
    signed char* __restrict__ Xq, signed char* __restrict__ Q1,
    signed char* __restrict__ Q2, float* __restrict__ s_arr,
    float* __restrict__ s1_arr)
{
    __shared__ __align__(16) char smem[4224];
    int bid = blockIdx.x;
    int tid = threadIdx.x;
    if (bid < 3072) {
        signed char (*tile)[65] = (signed char(*)[65])smem;
        int j0 = (bid % 96) * 64;
        int k0 = (bid / 96) * 64;
        const float* W = (j0 < 2048) ? Wf : (j0 < 4096) ? Wc : Wg;
        int jb = j0 & 2047;
        int c  = tid & 63;
        int rr = tid >> 6;
#pragma unroll
        for (int p = 0; p < 16; ++p) {
            int kl = p * 4 + rr;
            tile[kl][c] = (signed char)(int)W[(size_t)(k0 + kl) * DIM + jb + c];
        }
        __syncthreads();
#pragma unroll
        for (int p = 0; p < 16; ++p) {
            int jl = p * 4 + rr;
            WcatT[(size_t)(j0 + jl) * DIM + k0 + c] = tile[c][jl];
        }
    } else if (bid < 4096) {
        int idx = (bid - 3072) * 4096 + tid * 16;
#pragma unroll
        for (int p = 0; p < 4; ++p) {
            float4 v = *(const float4*)(Wg + idx + p * 4);
            char4 o;
            o.x = (signed char)(int)v.x; o.y = (signed char)(int)v.y;
            o.z = (signed char)(int)v.z; o.w = (signed char)(int)v.w;
            *(char4*)(Wgb + idx + p * 4) = o;
        }
    } else {
        float* red = (float*)smem;          // 12 floats
        float* tot = (float*)(smem + 64);   // 3 floats
        int row = bid - 4096;
        const float* xr = x + (size_t)row * DIM + tid * 8;
        const float* sr = scale + tid * 8;
        float4 a0 = *(const float4*)(xr);
        float4 a1 = *(const float4*)(xr + 4);
        float4 c0 = *(const float4*)(sr);
        float4 c1 = *(const float4*)(sr + 4);
        float xs[8] = {a0.x, a0.y, a0.z, a0.w, a1.x, a1.y, a1.z, a1.w};
        float sc[8] = {c0.x, c0.y, c0.z, c0.w, c1.x, c1.y, c1.z, c1.w};
        float sum = 0.f, mx2 = 0.f;
#pragma unroll
        for (int i = 0; i < 8; ++i) {
            sum += xs[i] * xs[i];
            mx2 = fmaxf(mx2, fabsf(xs[i]));
        }
#pragma unroll
        for (int off = 32; off > 0; off >>= 1) {
            sum += __shfl_down(sum, off);
            mx2 = fmaxf(mx2, __shfl_down(mx2, off));
        }
        int lane = tid & 63, wv = tid >> 6;
        if (lane == 0) { red[wv] = sum; red[4 + wv] = mx2; }
        __syncthreads();
        if (tid == 0) {
            tot[0] = red[0] + red[1] + red[2] + red[3];
            tot[1] = fmaxf(fmaxf(red[4], red[5]), fmaxf(red[6], red[7]));
        }
        __syncthreads();
        float rms = 1.0f / sqrtf(tot[0] * (1.0f / 2048.0f) + 1e-5f);
        float y[8]; float mx = 0.f;
#pragma unroll
        for (int i = 0; i < 8; ++i) {
            y[i] = (xs[i] * rms) * sc[i];
            mx = fmaxf(mx, fabsf(y[i]));
        }
#pragma unroll
        for (int off = 32; off > 0; off >>= 1) mx = fmaxf(mx, __shfl_down(mx, off));
        if (lane == 0) red[8 + wv] = mx;
        __syncthreads();
        if (tid == 0)
            tot[2] = fmaxf(fmaxf(red[8], red[9]), fmaxf(red[10], red[11]));
        __syncthreads();
        float s = 127.0f / (tot[2] + 1e-5f);
        s = fminf(fmaxf(s, 0.001f), 1000.0f);
        float s1 = 127.0f / (tot[1] + 1e-5f);
        float inv_s1 = 1.0f / s1;
        if (tid == 0) { s_arr[row] = s; s1_arr[row] = s1; }
        signed char q8[8], q1b[8], q2b[8];
#pragma unroll
        for (int i = 0; i < 8; ++i) {
            float q = fminf(fmaxf(rintf(s * y[i]), -128.f), 127.f);
            q8[i] = (signed char)(int)q;
            float qq1 = fminf(fmaxf(rintf(s1 * xs[i]), -128.f), 127.f);
            q1b[i] = (signed char)(int)qq1;
            float r = xs[i] - qq1 * inv_s1;
            float qq2 = fminf(fmaxf(rintf(s1 * 256.f * r), -128.f), 127.f);
            q2b[i] = (signed char)(int)qq2;
        }
        size_t o = (size_t)row * DIM + tid * 8;
        *(int2*)(Xq + o) = *(int2*)q8;
        *(int2*)(Q1 + o) = *(int2*)q1b;
        *(int2*)(Q2 + o) = *(int2*)q2b;
    }
}

// ---------------------------------------------------------------------------
// gemm_all: both GEMMs in one launch, interleaved 3:2 across the grid so
// fcg- and cg-blocks co-reside on each CU (MFMA pipe stays fed while the
// other type drains its barrier). Double-buffered LDS, ONE barrier per
// K-iter: stage(k+1) is issued right after the barrier, so its loads fly
// during the 16 MFMAs on tile k.
__global__ __launch_bounds__(256) void gemm_all(
    const signed char* __restrict__ Xq, const signed char* __restrict__ WcatT,
    const signed char* __restrict__ Q1, const signed char* __restrict__ Q2,
    const signed char* __restrict__ Wgb,
    const float* __restrict__ s_arr, const float* __restrict__ s1_arr,
    const float* __restrict__ b_f, const float* __restrict__ b_c,
    const float* __restrict__ b_g,
    unsigned short* __restrict__ FCG,   // (4096 x 6144) fp16
    unsigned short* __restrict__ U,     // cg*x  fp16
    unsigned short* __restrict__ V)     // 1-cg  fp16
{
    __shared__ __align__(16) signed char lds[32768];
    int bid = blockIdx.x;
    int grp = bid / 5, r5 = bid % 5;
    int tid = threadIdx.x;
    int lane = tid & 63, wv = tid >> 6;
    int lr = lane & 15, lq = lane >> 4;
    int rA = lane >> 2;
    int gch = ((lane & 3) ^ ((lane >> 3) & 3)) * 16;

    if (r5 < 3) {
        // ---- fcg path: 128x128 tile, 4 waves of 64x64 ----
        int fb = grp * 3 + r5;
        int m0 = (fb / 48) * 128;
        int n0 = (fb % 48) * 128;
        int wm = (wv >> 1) * 64, wn = (wv & 1) * 64;
        const signed char* Ab = Xq + (size_t)m0 * DIM;
        const signed char* Bb = WcatT + (size_t)n0 * DIM;

        int4v acc[4][4] = {};
        // stage tile 0 into buf0
#pragma unroll
        for (int it = 0; it < 2; ++it) {
            int region = wv + it * 4;
            int rr = region * 16 + rA;
            GLDS(Ab + (size_t)rr * DIM + gch, lds + region * 1024);
            GLDS(Bb + (size_t)rr * DIM + gch, lds + 8192 + region * 1024);
        }
        for (int k6 = 0; k6 < 32; ++k6) {
            signed char* cur = lds + (k6 & 1) * 16384;
            signed char* nxt = lds + ((k6 + 1) & 1) * 16384;
            __syncthreads();
            if (k6 + 1 < 32) {
                int kt = (k6 + 1) * 64;
#pragma unroll
                for (int it = 0; it < 2; ++it) {
                    int region = wv + it * 4;
                    int rr = region * 16 + rA;
                    GLDS(Ab + (size_t)rr * DIM + kt + gch, nxt + region * 1024);
                    GLDS(Bb + (size_t)rr * DIM + kt + gch, nxt + 8192 + region * 1024);
                }
            }
            int4v af[4], bb[4];
#pragma unroll
            for (int i = 0; i < 4; ++i) af[i] = frag_ld(cur, wm + i * 16 + lr, lq);
#pragma unroll
            for (int j = 0; j < 4; ++j) bb[j] = frag_ld(cur + 8192, wn + j * 16 + lr, lq);
#pragma unroll
            for (int i = 0; i < 4; ++i)
#pragma unroll
                for (int j = 0; j < 4; ++j)
                    acc[i][j] = __builtin_amdgcn_mfma_i32_16x16x64_i8(
                        af[i], bb[j], acc[i][j], 0, 0, 0);
        }
#pragma unroll
        for (int i = 0; i < 4; ++i) {
            float rinv[4];
#pragma unroll
            for (int r = 0; r < 4; ++r)
                rinv[r] = __builtin_amdgcn_rcpf(s_arr[m0 + wm + i * 16 + lq * 4 + r]);
#pragma unroll
            for (int j = 0; j < 4; ++j) {
                int gcol = n0 + wn + j * 16 + lr;
                int sec = gcol >> 11;
                int jj = gcol & 2047;
                float bias = (sec == 0) ? b_f[jj] : (sec == 1) ? b_c[jj] : b_g[jj];
#pragma unroll
                for (int r = 0; r < 4; ++r) {
                    int grow = m0 + wm + i * 16 + lq * 4 + r;
                    float z = fmaf((float)acc[i][j][r], rinv[r], bias);
                    float sg = fast_sigmoid(z);
                    FCG[(size_t)grow * NCAT + gcol] = f2h((sec == 1) ? z * sg : sg);
                }
            }
        }
    } else {
        // ---- cg path: 64x128 tile, 4 waves of 32x64, two i8 planes ----
        int cb = grp * 2 + (r5 - 3);
        int m0 = (cb >> 4) * 64;
        int n0 = (cb & 15) * 128;
        int wm = (wv >> 1) * 32, wn = (wv & 1) * 64;
        const signed char* A1b = Q1 + (size_t)m0 * DIM;
        const signed char* A2b = Q2 + (size_t)m0 * DIM;
        const signed char* Bb  = Wgb + (size_t)n0 * DIM;
        int r1 = wv * 16 + rA;

        int4v acc1[2][4] = {};
        int4v acc2[2][4] = {};
        // stage tile 0 into buf0 (As1@0 4KB, As2@4096, Bs@8192 8KB)
        {
            GLDS(A1b + (size_t)r1 * DIM + gch, lds + wv * 1024);
            GLDS(A2b + (size_t)r1 * DIM + gch, lds + 4096 + wv * 1024);
#pragma unroll
            for (int it = 0; it < 2; ++it) {
                int region = wv + it * 4;
                int rr = region * 16 + rA;
                GLDS(Bb + (size_t)rr * DIM + gch, lds + 8192 + region * 1024);
            }
        }
        for (int k6 = 0; k6 < 32; ++k6) {
            signed char* cur = lds + (k6 & 1) * 16384;
            signed char* nxt = lds + ((k6 + 1) & 1) * 16384;
            __syncthreads();
            if (k6 + 1 < 32) {
                int kt = (k6 + 1) * 64;
                GLDS(A1b + (size_t)r1 * DIM + kt + gch, nxt + wv * 1024);
                GLDS(A2b + (size_t)r1 * DIM + kt + gch, nxt + 4096 + wv * 1024);
#pragma unroll
                for (int it = 0; it < 2; ++it) {
                    int region = wv + it * 4;
                    int rr = region * 16 + rA;
                    GLDS(Bb + (size_t)rr * DIM + kt + gch, nxt + 8192 + region * 1024);
                }
            }
            int4v bb[4];
#pragma unroll
            for (int j = 0; j < 4; ++j) bb[j] = frag_ld(cur + 8192, wn + j * 16 + lr, lq);
#pragma unroll
            for (int i = 0; i < 2; ++i) {
                int4v a1 = frag_ld(cur, wm + i * 16 + lr, lq);
                int4v a2 = frag_ld(cur + 4096, wm + i * 16 + lr, lq);
#pragma unroll
                for (int j = 0; j < 4; ++j) {
                    acc1[i][j] = __builtin_amdgcn_mfma_i32_16x16x64_i8(
                        a1, bb[j], acc1[i][j], 0, 0, 0);
                    acc2[i][j] = __builtin_amdgcn_mfma_i32_16x16x64_i8(
                        a2, bb[j], acc2[i][j], 0, 0, 0);
                }
            }
        }
#pragma unroll
        for (int i = 0; i < 2; ++i) {
            float rinv[4];
#pragma unroll
            for (int r = 0; r < 4; ++r)
                rinv[r] = __builtin_amdgcn_rcpf(s1_arr[m0 + wm + i * 16 + lq * 4 + r]);
#pragma unroll
            for (int j = 0; j < 4; ++j) {
                int gcol = n0 + wn + j * 16 + lr;
#pragma unroll
                for (int r = 0; r < 4; ++r) {
                    int grow = m0 + wm + i * 16 + lq * 4 + r;
                    size_t go = (size_t)grow * DIM + gcol;
                    float zs = (float)acc1[i][j][r] + (float)acc2[i][j][r] * (1.f / 256.f);
                    float cg = fast_sigmoid(zs * rinv[r]);
                    // x reconstructed from the 2-plane quant (err <= ~5e-5)
                    float xv = ((float)Q1[go] + (float)Q2[go] * (1.f / 256.f)) * rinv[r];
                    U[go] = f2h(cg * xv);
                    V[go] = f2h(1.f - cg);
                }
            }
        }
    }
}

// ---------------------------------------------------------------------------
// Scan phase 1: 2 chains/thread. h_t = A h + B, A = v*f, B = v*(1-f)*c + u.
__global__ __launch_bounds__(256) void scan_partial(
    const unsigned short* __restrict__ FCG, const unsigned short* __restrict__ U,
    const unsigned short* __restrict__ V, float4* __restrict__ PQ4)
{
    int tp = blockIdx.x * 256 + threadIdx.x;   // pair 0..1023
    int c = blockIdx.y;
    int b = blockIdx.z;
    int h0 = tp * 2;
    size_t r0 = (size_t)(b * 512 + c * TCHUNK);
    const unsigned short* fp = FCG + r0 * NCAT + h0;
    const unsigned short* up = U + r0 * DIM + h0;
    const unsigned short* vp = V + r0 * DIM + h0;
    float P0 = 1.f, Q0 = 0.f, P1 = 1.f, Q1v = 0.f;
#pragma unroll 4
    for (int t = 0; t < TCHUNK; ++t) {
        unsigned fw = *(const unsigned*)(fp);
        unsigned cw = *(const unsigned*)(fp + 2048);
        unsigned uw = *(const unsigned*)(up);
        unsigned vw = *(const unsigned*)(vp);
        float f0 = h2f(fw & 0xffff), f1 = h2f(fw >> 16);
        float c0 = h2f(cw & 0xffff), c1 = h2f(cw >> 16);
        float u0 = h2f(uw & 0xffff), u1 = h2f(uw >> 16);
        float v0 = h2f(vw & 0xffff), v1 = h2f(vw >> 16);
        float A0 = v0 * f0, A1 = v1 * f1;
        float B0 = fmaf(v0 * (1.f - f0), c0, u0);
        float B1 = fmaf(v1 * (1.f - f1), c1, u1);
        P0 = A0 * P0; Q0 = fmaf(A0, Q0, B0);
        P1 = A1 * P1; Q1v = fmaf(A1, Q1v, B1);
        fp += NCAT; up += DIM; vp += DIM;
    }
    float4 o; o.x = P0; o.y = Q0; o.z = P1; o.w = Q1v;
    PQ4[(size_t)c * 8192 + b * 1024 + tp] = o;
}

// Scan phase 3 (mid folded in): recombine chunk summaries for entry h, then
// replay 32 steps and emit o_t (fp32).
__global__ __launch_bounds__(256) void scan_final(
    const unsigned short* __restrict__ FCG, const unsigned short* __restrict__ U,
    const unsigned short* __restrict__ V, const float4* __restrict__ PQ4,
    float* __restrict__ out)
{
    int tp = blockIdx.x * 256 + threadIdx.x;
    int c = blockIdx.y;
    int b = blockIdx.z;
    int h0 = tp * 2;
    float h0s = 0.f, h1s = 0.f;
    for (int cc = 0; cc < c; ++cc) {
        float4 pq = PQ4[(size_t)cc * 8192 + b * 1024 + tp];
        h0s = fmaf(pq.x, h0s, pq.y);
        h1s = fmaf(pq.z, h1s, pq.w);
    }
    size_t r0 = (size_t)(b * 512 + c * TCHUNK);
    const unsigned short* fp = FCG + r0 * NCAT + h0;
    const unsigned short* up = U + r0 * DIM + h0;
    const unsigned short* vp = V + r0 * DIM + h0;
    float* op = out + r0 * DIM + h0;
#pragma unroll 4
    for (int t = 0; t < TCHUNK; ++t) {
        unsigned fw = *(const unsigned*)(fp);
        unsigned cw = *(const unsigned*)(fp + 2048);
        unsigned gw = *(const unsigned*)(fp + 4096);
        unsigned uw = *(const unsigned*)(up);
        unsigned vw = *(const unsigned*)(vp);
        float f0 = h2f(fw & 0xffff), f1 = h2f(fw >> 16);
        float c0 = h2f(cw & 0xffff), c1 = h2f(cw >> 16);
        float g0 = h2f(gw & 0xffff), g1 = h2f(gw >> 16);
        float u0 = h2f(uw & 0xffff), u1 = h2f(uw >> 16);
        float v0 = h2f(vw & 0xffff), v1 = h2f(vw >> 16);
        float hn0 = f0 * h0s + (1.f - f0) * c0;
        float hn1 = f1 * h1s + (1.f - f1) * c1;
        float2 ov; ov.x = g0 * hn0; ov.y = g1 * hn1;
        *(float2*)op = ov;
        h0s = fmaf(v0, hn0, u0);
        h1s = fmaf(v1, hn1, u1);
        fp += NCAT; up += DIM; vp += DIM; op += DIM;
    }
}

// ---------------------------------------------------------------------------
extern "C" void kernel_launch(void* const* d_in, const int* in_sizes, int n_in,
                              void* d_out, int out_size, void* d_ws, size_t ws_size,
                              hipStream_t stream) {
    const float* x     = (const float*)d_in[0];
    const float* rmssc = (const float*)d_in[1];
    const float* W_f   = (const float*)d_in[2];
    const float* W_c   = (const float*)d_in[3];
    const float* W_g   = (const float*)d_in[4];
    const float* b_f   = (const float*)d_in[5];
    const float* b_c   = (const float*)d_in[6];
    const float* b_g   = (const float*)d_in[7];
    float* out = (float*)d_out;

    char* ws = (char*)d_ws;
    size_t off = 0;
    auto alloc = [&](size_t bytes) -> void* {
        void* p = ws + off;
        off += (bytes + 255) & ~(size_t)255;
        return p;
    };
    signed char* WcatT = (signed char*)alloc((size_t)NCAT * DIM);
    signed char* Wgb   = (signed char*)alloc((size_t)DIM * DIM);
    signed char* Xq    = (signed char*)alloc((size_t)RTOT * DIM);
    signed char* Q1    = (signed char*)alloc((size_t)RTOT * DIM);
    signed char* Q2    = (signed char*)alloc((size_t)RTOT * DIM);
    float* s_arr       = (float*)alloc((size_t)RTOT * 4);
    float* s1_arr      = (float*)alloc((size_t)RTOT * 4);
    unsigned short* FCG = (unsigned short*)alloc((size_t)RTOT * NCAT * 2);
    unsigned short* U   = (unsigned short*)alloc((size_t)RTOT * DIM * 2);
    unsigned short* V   = (unsigned short*)alloc((size_t)RTOT * DIM * 2);
    float4* PQ4        = (float4*)alloc((size_t)NCHUNK * 8192 * 16);

    hipLaunchKernelGGL(prep_all, dim3(8192), dim3(256), 0, stream,
                       x, rmssc, W_f, W_c, W_g, WcatT, Wgb, Xq, Q1, Q2,
                       s_arr, s1_arr);
    hipLaunchKernelGGL(gemm_all, dim3(2560), dim3(256), 0, stream,
                       Xq, WcatT, Q1, Q2, Wgb, s_arr, s1_arr,
                       b_f, b_c, b_g, FCG, U, V);
    hipLaunchKernelGGL(scan_partial, dim3(DIM / 512, NCHUNK, 8), dim3(256), 0, stream,
                       FCG, U, V, PQ4);
    hipLaunchKernelGGL(scan_final, dim3(DIM / 512, NCHUNK, 8), dim3(256), 0, stream,
                       FCG, U, V, PQ4, out);
}